// Round 5
// baseline (112.463 us; speedup 1.0000x reference)
//
#include <hip/hip_runtime.h>

#define NBINS   1024
#define CAPC    4096
#define TARGETC 256
#define DET     100
#define XCLIP   4.135166556742356f
#define SUBROWS 16
#define K1BLK   256

__device__ inline float scalar_to_float(const int* p) {
  int v = *p;
  return (v >= 0 && v < (1 << 20)) ? (float)v : __int_as_float(v);
}

struct Box { float x1, y1, x2, y2; };

__device__ inline Box decode_clip(float4 r, float4 p, float W, float H) {
  float w = p.z - p.x, h = p.w - p.y;
  float cx = p.x + 0.5f * w, cy = p.y + 0.5f * h;
  float dx = r.x / 10.f, dy = r.y / 10.f;
  float dw = fminf(r.z / 5.f, XCLIP), dh = fminf(r.w / 5.f, XCLIP);
  float pcx = dx * w + cx, pcy = dy * h + cy;
  float pw = __expf(dw) * w, ph = __expf(dh) * h;
  Box b;
  b.x1 = fminf(fmaxf(pcx - 0.5f * pw, 0.f), W);
  b.y1 = fminf(fmaxf(pcy - 0.5f * ph, 0.f), H);
  b.x2 = fminf(fmaxf(pcx + 0.5f * pw, 0.f), W);
  b.y2 = fminf(fmaxf(pcy + 0.5f * ph, 0.f), H);
  return b;
}

__device__ inline float iou_f(const Box& a, const Box& b) {
  float area1 = (a.x2 - a.x1) * (a.y2 - a.y1);
  float area2 = (b.x2 - b.x1) * (b.y2 - b.y1);
  float lx = fmaxf(a.x1, b.x1), ly = fmaxf(a.y1, b.y1);
  float rx = fminf(a.x2, b.x2), ry = fminf(a.y2, b.y2);
  float w = fmaxf(rx - lx, 0.f), h = fmaxf(ry - ly, 0.f);
  float inter = w * h;
  return inter / (area1 + area2 - inter);
}

// K1 v5: barrier-free per-wave 16-row subtiles. Each wave stages its own
// 5824B LDS slice (coalesced float4), wave-local lgkmcnt drain (no block
// barrier), 4 lanes/row single-pass max/argmax/expsum. 20 independent
// waves/CU keep HBM streaming (no lockstep).
__global__ __launch_bounds__(K1BLK) void k1_score(
    const float* __restrict__ logits, const float* __restrict__ reg,
    const float* __restrict__ prop, const int* __restrict__ ph,
    const int* __restrict__ pw, float* __restrict__ scores,
    int* __restrict__ labels, unsigned int* __restrict__ hist, int N) {
  __shared__ float tile[4 * SUBROWS * 91];   // 23296 B (5824 per wave)
  __shared__ unsigned int lh[NBINS];         // 4096 B
  const int t = threadIdx.x;
  const int w = t >> 6, lane = t & 63;
  for (int i = t; i < NBINS; i += K1BLK) lh[i] = 0u;
  __syncthreads();
  const float W = scalar_to_float(pw), H = scalar_to_float(ph);
  const int sub = blockIdx.x * 4 + w;
  const int base = sub * SUBROWS;
  float* wt = tile + w * (SUBROWS * 91);
  if (base < N) {
    const int rows = min(SUBROWS, N - base);
    const int nf = rows * 91, nf4 = nf >> 2;
    const float4* s4 = (const float4*)(logits + (size_t)base * 91);  // 5824B-aligned
    #pragma unroll
    for (int k = 0; k < 6; ++k) {
      int i = lane + (k << 6);
      if (i < nf4) ((float4*)wt)[i] = s4[i];
    }
    for (int i = (nf4 << 2) + lane; i < nf; i += 64)   // only when rows<16
      wt[i] = logits[(size_t)base * 91 + i];
    asm volatile("s_waitcnt lgkmcnt(0)" ::: "memory");
    __builtin_amdgcn_wave_barrier();
    const int r = lane >> 2, s = lane & 3;
    if (r < rows) {
      const float* rowp = wt + r * 91;
      float mv = -3.402823466e38f; int mi = 1 << 20;
      float e0 = 0.f, e1 = 0.f;
      #pragma unroll
      for (int k = 0; k < 23; ++k) {
        int j = s + (k << 2);
        if (j < 91) {
          float v = rowp[j];
          float ex = __expf(v);
          if (k & 1) e1 += ex; else e0 += ex;
          if (v > mv) { mv = v; mi = j; }
        }
      }
      float e = e0 + e1;
      #pragma unroll
      for (int m = 1; m <= 2; m <<= 1) {
        float ov = __shfl_xor(mv, m, 64);
        int   oi = __shfl_xor(mi, m, 64);
        float oe = __shfl_xor(e, m, 64);
        e += oe;
        if (ov > mv || (ov == mv && oi < mi)) { mv = ov; mi = oi; }
      }
      if (s == 0) {
        float top1 = __expf(mv) / e;
        const int row = base + r;
        float4 rg = ((const float4*)reg)[row];
        float4 pp = ((const float4*)prop)[row];
        Box b = decode_clip(rg, pp, W, H);
        bool valid = (top1 > 0.05f) && ((b.x2 - b.x1) >= 0.01f) && ((b.y2 - b.y1) >= 0.01f);
        float sc = valid ? top1 : -1.f;
        scores[row] = sc;
        labels[row] = mi;
        if (sc > 0.f) {
          int bin = (int)(sc * (float)NBINS);
          if (bin > NBINS - 1) bin = NBINS - 1;
          atomicAdd(&lh[bin], 1u);
        }
      }
    }
  }
  __syncthreads();
  for (int i = t; i < NBINS; i += K1BLK) {
    unsigned int cu = lh[i];
    if (cu) atomicAdd(&hist[i], cu);
  }
}

// K2: wave-shuffle suffix scan (2 barriers), then compaction.
__global__ __launch_bounds__(1024) void k2_compact(
    const float* __restrict__ scores, const unsigned int* __restrict__ hist,
    unsigned long long* __restrict__ cand, unsigned int* __restrict__ counter, int N) {
  __shared__ unsigned int wsum[16];
  __shared__ unsigned int wtail[16];
  __shared__ int bstar;
  const int t = threadIdx.x;
  const int lane = t & 63, w = t >> 6;
  const unsigned int h0 = hist[t];
  unsigned int v = h0;
  #pragma unroll
  for (int m = 1; m < 64; m <<= 1) {
    unsigned int o = __shfl_down(v, m, 64);
    if (lane + m < 64) v += o;
  }
  if (lane == 0) wsum[w] = v;
  if (t == 0) bstar = 0;
  __syncthreads();
  if (w == 0) {
    unsigned int u = (lane < 16) ? wsum[lane] : 0u;
    unsigned int inc = u;
    #pragma unroll
    for (int m = 1; m < 16; m <<= 1) {
      unsigned int o = __shfl_down(inc, m, 64);
      if (lane + m < 16) inc += o;
    }
    if (lane < 16) wtail[lane] = inc - u;
  }
  __syncthreads();
  unsigned int St = v + wtail[w];
  unsigned int St1 = St - h0;
  if (St >= TARGETC && St1 < TARGETC) {
    int b = t;
    if (St > CAPC) b = t + 1;
    if (b > NBINS - 1) b = NBINS - 1;
    bstar = b;
  }
  __syncthreads();
  const int bs = bstar;
  for (int i = blockIdx.x * blockDim.x + t; i < N; i += gridDim.x * blockDim.x) {
    float sc = scores[i];
    if (sc > 0.f) {
      int bin = (int)(sc * (float)NBINS);
      if (bin > NBINS - 1) bin = NBINS - 1;
      if (bin >= bs) {
        unsigned int pos = atomicAdd(counter, 1u);
        if (pos < CAPC) {
          unsigned long long key =
              ((unsigned long long)__float_as_uint(sc) << 32) |
              (unsigned long long)(0xFFFFFFFFu - (unsigned int)i);
          cand[pos] = key;
        }
      }
    }
  }
}

// K3: single block. bitonic sort over next-pow2(count), chunked greedy NMS, output.
__global__ __launch_bounds__(1024) void k3_nms(
    const unsigned long long* __restrict__ cand, const unsigned int* __restrict__ counter,
    const float* __restrict__ reg, const float* __restrict__ prop,
    const int* __restrict__ labels, const int* __restrict__ ph,
    const int* __restrict__ pw, float* __restrict__ out) {
  __shared__ unsigned long long keys[CAPC];
  __shared__ Box kbox[DET];
  __shared__ int klab[DET];
  __shared__ float kscore[DET];
  __shared__ Box cbox[64];
  __shared__ int clab[64];
  __shared__ float cscore[64];
  __shared__ unsigned int supk[64];
  __shared__ unsigned int rowm[64][2];
  __shared__ int nkept;
  const int t = threadIdx.x;
  unsigned int cnt_u = *counter;
  int count = (cnt_u < (unsigned int)CAPC) ? (int)cnt_u : CAPC;
  int P = 1;
  while (P < count) P <<= 1;
  if (P < 2) P = 2;
  for (int i = t; i < P; i += 1024) keys[i] = (i < count) ? cand[i] : 0ULL;
  if (t == 0) nkept = 0;
  __syncthreads();
  for (int k = 2; k <= P; k <<= 1) {
    for (int j = k >> 1; j > 0; j >>= 1) {
      for (int i = t; i < P; i += 1024) {
        int ixj = i ^ j;
        if (ixj > i) {
          unsigned long long a = keys[i], b = keys[ixj];
          bool sw = ((i & k) == 0) ? (a < b) : (a > b);
          if (sw) { keys[i] = b; keys[ixj] = a; }
        }
      }
      __syncthreads();
    }
  }
  const float W = scalar_to_float(pw), H = scalar_to_float(ph);
  for (int base = 0; base < count && nkept < DET; base += 64) {
    int nc = count - base; if (nc > 64) nc = 64;
    if (t < 64) { supk[t] = 0u; rowm[t][0] = 0u; rowm[t][1] = 0u; }
    if (t < nc) {
      unsigned long long key = keys[base + t];
      int row = (int)(0xFFFFFFFFu - (unsigned int)(key & 0xFFFFFFFFULL));
      cscore[t] = __uint_as_float((unsigned int)(key >> 32));
      clab[t] = labels[row];
      float4 r = ((const float4*)reg)[row];
      float4 p = ((const float4*)prop)[row];
      cbox[t] = decode_clip(r, p, W, H);
    }
    __syncthreads();
    int nk = nkept;
    {
      int c = t >> 4, kk = t & 15;
      if (c < nc) {
        unsigned int hit = 0u;
        for (int j = kk; j < nk; j += 16) {
          if (clab[c] == klab[j] && iou_f(cbox[c], kbox[j]) > 0.5f) { hit = 1u; break; }
        }
        if (hit) atomicOr(&supk[c], 1u);
      }
    }
    for (int p4 = t; p4 < 64 * 64; p4 += 1024) {
      int a = p4 >> 6, b = p4 & 63;
      if (a < b && b < nc) {
        if (clab[a] == clab[b] && iou_f(cbox[a], cbox[b]) > 0.5f)
          atomicOr(&rowm[a][b >> 5], 1u << (b & 31));
      }
    }
    __syncthreads();
    if (t == 0) {
      unsigned int s0 = 0u, s1 = 0u;
      int nkl = nkept;
      for (int j = 0; j < nc && nkl < DET; ++j) {
        unsigned int bit = (j < 32) ? ((s0 >> j) & 1u) : ((s1 >> (j - 32)) & 1u);
        if (!supk[j] && !bit) {
          kbox[nkl] = cbox[j];
          klab[nkl] = clab[j];
          kscore[nkl] = cscore[j];
          ++nkl;
          s0 |= rowm[j][0];
          s1 |= rowm[j][1];
        }
      }
      nkept = nkl;
    }
    __syncthreads();
  }
  int nk = nkept;
  if (t < DET) {
    bool v = t < nk;
    Box b = v ? kbox[t] : Box{0.f, 0.f, 0.f, 0.f};
    out[t * 4 + 0] = b.x1;
    out[t * 4 + 1] = b.y1;
    out[t * 4 + 2] = b.x2;
    out[t * 4 + 3] = b.y2;
    out[400 + t] = v ? kscore[t] : 0.f;
    out[500 + t] = v ? (float)klab[t] : -1.f;
  }
}

extern "C" void kernel_launch(void* const* d_in, const int* in_sizes, int n_in,
                              void* d_out, int out_size, void* d_ws, size_t ws_size,
                              hipStream_t stream) {
  const float* logits = (const float*)d_in[0];
  const float* reg    = (const float*)d_in[1];
  const float* prop   = (const float*)d_in[2];
  const int*   ph     = (const int*)d_in[3];
  const int*   pw     = (const int*)d_in[4];
  float* out = (float*)d_out;

  const int N = in_sizes[1] / 4;

  char* ws = (char*)d_ws;
  float* scores = (float*)ws;                                  // N f32
  int* labels   = (int*)(ws + (size_t)N * 4);                  // N i32
  size_t off = (size_t)N * 8;
  off = (off + 255) & ~(size_t)255;
  unsigned int* hist = (unsigned int*)(ws + off);              // NBINS u32
  unsigned int* counter = hist + NBINS;                        // 1 u32
  unsigned long long* cand = (unsigned long long*)(ws + off + NBINS * 4 + 64); // CAPC u64

  const int nsub = (N + SUBROWS - 1) / SUBROWS;
  const int grid = (nsub + 3) / 4;

  hipMemsetAsync(hist, 0, NBINS * 4 + 64, stream);
  k1_score<<<grid, K1BLK, 0, stream>>>(logits, reg, prop, ph, pw, scores, labels, hist, N);
  k2_compact<<<256, 1024, 0, stream>>>(scores, hist, cand, counter, N);
  k3_nms<<<1, 1024, 0, stream>>>(cand, counter, reg, prop, labels, ph, pw, out);
}

// Round 6
// 91.872 us; speedup vs baseline: 1.2241x; 1.2241x over previous
//
#include <hip/hip_runtime.h>

#define NBINS   1024
#define CAPC    4096
#define TARGETC 256
#define DET     100
#define XCLIP   4.135166556742356f
#define CHUNK   64
#define K1BLK   256

__device__ inline float scalar_to_float(const int* p) {
  int v = *p;
  return (v >= 0 && v < (1 << 20)) ? (float)v : __int_as_float(v);
}

struct Box { float x1, y1, x2, y2; };

__device__ inline Box decode_clip(float4 r, float4 p, float W, float H) {
  float w = p.z - p.x, h = p.w - p.y;
  float cx = p.x + 0.5f * w, cy = p.y + 0.5f * h;
  float dx = r.x / 10.f, dy = r.y / 10.f;
  float dw = fminf(r.z / 5.f, XCLIP), dh = fminf(r.w / 5.f, XCLIP);
  float pcx = dx * w + cx, pcy = dy * h + cy;
  float pw = __expf(dw) * w, ph = __expf(dh) * h;
  Box b;
  b.x1 = fminf(fmaxf(pcx - 0.5f * pw, 0.f), W);
  b.y1 = fminf(fmaxf(pcy - 0.5f * ph, 0.f), H);
  b.x2 = fminf(fmaxf(pcx + 0.5f * pw, 0.f), W);
  b.y2 = fminf(fmaxf(pcy + 0.5f * ph, 0.f), H);
  return b;
}

__device__ inline float iou_f(const Box& a, const Box& b) {
  float area1 = (a.x2 - a.x1) * (a.y2 - a.y1);
  float area2 = (b.x2 - b.x1) * (b.y2 - b.y1);
  float lx = fmaxf(a.x1, b.x1), ly = fmaxf(a.y1, b.y1);
  float rx = fminf(a.x2, b.x2), ry = fminf(a.y2, b.y2);
  float w = fmaxf(rx - lx, 0.f), h = fmaxf(ry - ly, 0.f);
  float inter = w * h;
  return inter / (area1 + area2 - inter);
}

// K0: zero hist + counter (replaces hipMemsetAsync / rocclr fillBuffer).
__global__ __launch_bounds__(256) void k0_zero(unsigned int* __restrict__ hist) {
  int t = blockIdx.x * 256 + threadIdx.x;
  if (t < NBINS + 16) hist[t] = 0u;
}

// K1 v6: persistent blocks, double-buffered LDS tile, register prefetch
// issued BEFORE compute so global loads are in flight during the whole
// compute phase; one barrier per iteration. Chunk stride = gridDim keeps
// the aggregate read stream sequential.
__global__ __launch_bounds__(K1BLK) void k1_score(
    const float* __restrict__ logits, const float* __restrict__ reg,
    const float* __restrict__ prop, const int* __restrict__ ph,
    const int* __restrict__ pw, float* __restrict__ scores,
    int* __restrict__ labels, unsigned int* __restrict__ hist, int N) {
  __shared__ float tile[2][CHUNK * 91];   // 2 x 23296 B
  __shared__ unsigned int lh[NBINS];      // 4096 B
  const int t = threadIdx.x;
  for (int i = t; i < NBINS; i += K1BLK) lh[i] = 0u;
  const float W = scalar_to_float(pw), H = scalar_to_float(ph);
  const int nchunks = (N + CHUNK - 1) / CHUNK;

  float4 R[6];
  auto load_chunk = [&](int cc) {
    const int nf4 = (min(CHUNK, N - cc * CHUNK) * 91) >> 2;
    const float4* s4 = (const float4*)(logits + (size_t)cc * CHUNK * 91);
    #pragma unroll
    for (int k = 0; k < 6; ++k) {
      int i = t + (k << 8);
      if (i < nf4) R[k] = s4[i];
    }
  };
  auto store_tile = [&](float* dst, int cc) {
    const int nf = min(CHUNK, N - cc * CHUNK) * 91;
    const int nf4 = nf >> 2;
    #pragma unroll
    for (int k = 0; k < 6; ++k) {
      int i = t + (k << 8);
      if (i < nf4) ((float4*)dst)[i] = R[k];
    }
    for (int i = (nf4 << 2) + t; i < nf; i += K1BLK)   // partial last chunk only
      dst[i] = logits[(size_t)cc * CHUNK * 91 + i];
  };

  int c = blockIdx.x;
  int cur = 0;
  if (c < nchunks) { load_chunk(c); store_tile(tile[0], c); }
  __syncthreads();
  while (c < nchunks) {
    const int cn = c + gridDim.x;
    if (cn < nchunks) load_chunk(cn);      // prefetch: in flight during compute
    // ---- compute chunk c from tile[cur] ----
    const int rows = min(CHUNK, N - c * CHUNK);
    const int r = t >> 2, s = t & 3;
    if (r < rows) {
      const float* rowp = tile[cur] + r * 91;
      float mv = -3.402823466e38f; int mi = 1 << 20;
      float e0 = 0.f, e1 = 0.f;
      #pragma unroll
      for (int k = 0; k < 23; ++k) {
        int j = s + (k << 2);
        if (j < 91) {
          float v = rowp[j];
          float ex = __expf(v);
          if (k & 1) e1 += ex; else e0 += ex;
          if (v > mv) { mv = v; mi = j; }
        }
      }
      float e = e0 + e1;
      #pragma unroll
      for (int m = 1; m <= 2; m <<= 1) {
        float ov = __shfl_xor(mv, m, 64);
        int   oi = __shfl_xor(mi, m, 64);
        float oe = __shfl_xor(e, m, 64);
        e += oe;
        if (ov > mv || (ov == mv && oi < mi)) { mv = ov; mi = oi; }
      }
      if (s == 0) {
        float top1 = __expf(mv) / e;
        const int row = c * CHUNK + r;
        float4 rg = ((const float4*)reg)[row];
        float4 pp = ((const float4*)prop)[row];
        Box b = decode_clip(rg, pp, W, H);
        bool valid = (top1 > 0.05f) && ((b.x2 - b.x1) >= 0.01f) && ((b.y2 - b.y1) >= 0.01f);
        float sc = valid ? top1 : -1.f;
        scores[row] = sc;
        labels[row] = mi;
        if (sc > 0.f) {
          int bin = (int)(sc * (float)NBINS);
          if (bin > NBINS - 1) bin = NBINS - 1;
          atomicAdd(&lh[bin], 1u);
        }
      }
    }
    // ---- stage prefetched chunk into the other buffer ----
    if (cn < nchunks) store_tile(tile[cur ^ 1], cn);
    __syncthreads();
    cur ^= 1;
    c = cn;
  }
  __syncthreads();
  for (int i = t; i < NBINS; i += K1BLK) {
    unsigned int cu = lh[i];
    if (cu) atomicAdd(&hist[i], cu);
  }
}

// K2: wave-shuffle suffix scan (2 barriers), then compaction.
__global__ __launch_bounds__(1024) void k2_compact(
    const float* __restrict__ scores, const unsigned int* __restrict__ hist,
    unsigned long long* __restrict__ cand, unsigned int* __restrict__ counter, int N) {
  __shared__ unsigned int wsum[16];
  __shared__ unsigned int wtail[16];
  __shared__ int bstar;
  const int t = threadIdx.x;
  const int lane = t & 63, w = t >> 6;
  const unsigned int h0 = hist[t];
  unsigned int v = h0;
  #pragma unroll
  for (int m = 1; m < 64; m <<= 1) {
    unsigned int o = __shfl_down(v, m, 64);
    if (lane + m < 64) v += o;
  }
  if (lane == 0) wsum[w] = v;
  if (t == 0) bstar = 0;
  __syncthreads();
  if (w == 0) {
    unsigned int u = (lane < 16) ? wsum[lane] : 0u;
    unsigned int inc = u;
    #pragma unroll
    for (int m = 1; m < 16; m <<= 1) {
      unsigned int o = __shfl_down(inc, m, 64);
      if (lane + m < 16) inc += o;
    }
    if (lane < 16) wtail[lane] = inc - u;
  }
  __syncthreads();
  unsigned int St = v + wtail[w];
  unsigned int St1 = St - h0;
  if (St >= TARGETC && St1 < TARGETC) {
    int b = t;
    if (St > CAPC) b = t + 1;
    if (b > NBINS - 1) b = NBINS - 1;
    bstar = b;
  }
  __syncthreads();
  const int bs = bstar;
  for (int i = blockIdx.x * blockDim.x + t; i < N; i += gridDim.x * blockDim.x) {
    float sc = scores[i];
    if (sc > 0.f) {
      int bin = (int)(sc * (float)NBINS);
      if (bin > NBINS - 1) bin = NBINS - 1;
      if (bin >= bs) {
        unsigned int pos = atomicAdd(counter, 1u);
        if (pos < CAPC) {
          unsigned long long key =
              ((unsigned long long)__float_as_uint(sc) << 32) |
              (unsigned long long)(0xFFFFFFFFu - (unsigned int)i);
          cand[pos] = key;
        }
      }
    }
  }
}

// K3: single block. bitonic sort over next-pow2(count), chunked greedy NMS, output.
__global__ __launch_bounds__(1024) void k3_nms(
    const unsigned long long* __restrict__ cand, const unsigned int* __restrict__ counter,
    const float* __restrict__ reg, const float* __restrict__ prop,
    const int* __restrict__ labels, const int* __restrict__ ph,
    const int* __restrict__ pw, float* __restrict__ out) {
  __shared__ unsigned long long keys[CAPC];
  __shared__ Box kbox[DET];
  __shared__ int klab[DET];
  __shared__ float kscore[DET];
  __shared__ Box cbox[64];
  __shared__ int clab[64];
  __shared__ float cscore[64];
  __shared__ unsigned int supk[64];
  __shared__ unsigned int rowm[64][2];
  __shared__ int nkept;
  const int t = threadIdx.x;
  unsigned int cnt_u = *counter;
  int count = (cnt_u < (unsigned int)CAPC) ? (int)cnt_u : CAPC;
  int P = 1;
  while (P < count) P <<= 1;
  if (P < 2) P = 2;
  for (int i = t; i < P; i += 1024) keys[i] = (i < count) ? cand[i] : 0ULL;
  if (t == 0) nkept = 0;
  __syncthreads();
  for (int k = 2; k <= P; k <<= 1) {
    for (int j = k >> 1; j > 0; j >>= 1) {
      for (int i = t; i < P; i += 1024) {
        int ixj = i ^ j;
        if (ixj > i) {
          unsigned long long a = keys[i], b = keys[ixj];
          bool sw = ((i & k) == 0) ? (a < b) : (a > b);
          if (sw) { keys[i] = b; keys[ixj] = a; }
        }
      }
      __syncthreads();
    }
  }
  const float W = scalar_to_float(pw), H = scalar_to_float(ph);
  for (int base = 0; base < count && nkept < DET; base += 64) {
    int nc = count - base; if (nc > 64) nc = 64;
    if (t < 64) { supk[t] = 0u; rowm[t][0] = 0u; rowm[t][1] = 0u; }
    if (t < nc) {
      unsigned long long key = keys[base + t];
      int row = (int)(0xFFFFFFFFu - (unsigned int)(key & 0xFFFFFFFFULL));
      cscore[t] = __uint_as_float((unsigned int)(key >> 32));
      clab[t] = labels[row];
      float4 r = ((const float4*)reg)[row];
      float4 p = ((const float4*)prop)[row];
      cbox[t] = decode_clip(r, p, W, H);
    }
    __syncthreads();
    int nk = nkept;
    {
      int c = t >> 4, kk = t & 15;
      if (c < nc) {
        unsigned int hit = 0u;
        for (int j = kk; j < nk; j += 16) {
          if (clab[c] == klab[j] && iou_f(cbox[c], kbox[j]) > 0.5f) { hit = 1u; break; }
        }
        if (hit) atomicOr(&supk[c], 1u);
      }
    }
    for (int p4 = t; p4 < 64 * 64; p4 += 1024) {
      int a = p4 >> 6, b = p4 & 63;
      if (a < b && b < nc) {
        if (clab[a] == clab[b] && iou_f(cbox[a], cbox[b]) > 0.5f)
          atomicOr(&rowm[a][b >> 5], 1u << (b & 31));
      }
    }
    __syncthreads();
    if (t == 0) {
      unsigned int s0 = 0u, s1 = 0u;
      int nkl = nkept;
      for (int j = 0; j < nc && nkl < DET; ++j) {
        unsigned int bit = (j < 32) ? ((s0 >> j) & 1u) : ((s1 >> (j - 32)) & 1u);
        if (!supk[j] && !bit) {
          kbox[nkl] = cbox[j];
          klab[nkl] = clab[j];
          kscore[nkl] = cscore[j];
          ++nkl;
          s0 |= rowm[j][0];
          s1 |= rowm[j][1];
        }
      }
      nkept = nkl;
    }
    __syncthreads();
  }
  int nk = nkept;
  if (t < DET) {
    bool v = t < nk;
    Box b = v ? kbox[t] : Box{0.f, 0.f, 0.f, 0.f};
    out[t * 4 + 0] = b.x1;
    out[t * 4 + 1] = b.y1;
    out[t * 4 + 2] = b.x2;
    out[t * 4 + 3] = b.y2;
    out[400 + t] = v ? kscore[t] : 0.f;
    out[500 + t] = v ? (float)klab[t] : -1.f;
  }
}

extern "C" void kernel_launch(void* const* d_in, const int* in_sizes, int n_in,
                              void* d_out, int out_size, void* d_ws, size_t ws_size,
                              hipStream_t stream) {
  const float* logits = (const float*)d_in[0];
  const float* reg    = (const float*)d_in[1];
  const float* prop   = (const float*)d_in[2];
  const int*   ph     = (const int*)d_in[3];
  const int*   pw     = (const int*)d_in[4];
  float* out = (float*)d_out;

  const int N = in_sizes[1] / 4;

  char* ws = (char*)d_ws;
  float* scores = (float*)ws;                                  // N f32
  int* labels   = (int*)(ws + (size_t)N * 4);                  // N i32
  size_t off = (size_t)N * 8;
  off = (off + 255) & ~(size_t)255;
  unsigned int* hist = (unsigned int*)(ws + off);              // NBINS u32
  unsigned int* counter = hist + NBINS;                        // 1 u32
  unsigned long long* cand = (unsigned long long*)(ws + off + NBINS * 4 + 64); // CAPC u64

  k0_zero<<<(NBINS + 16 + 255) / 256, 256, 0, stream>>>(hist);
  k1_score<<<768, K1BLK, 0, stream>>>(logits, reg, prop, ph, pw, scores, labels, hist, N);
  k2_compact<<<256, 1024, 0, stream>>>(scores, hist, cand, counter, N);
  k3_nms<<<1, 1024, 0, stream>>>(cand, counter, reg, prop, labels, ph, pw, out);
}

// Round 7
// 72.743 us; speedup vs baseline: 1.5460x; 1.2630x over previous
//
#include <hip/hip_runtime.h>

#define NBINS   1024
#define CAPC    4096
#define TARGETC 256
#define DET     100
#define XCLIP   4.135166556742356f
#define CHUNK   64
#define K1BLK   256
#define TILEF   5888   // 5824 floats + 64-float pad (tail-slot overflow)

__device__ inline float scalar_to_float(const int* p) {
  int v = *p;
  return (v >= 0 && v < (1 << 20)) ? (float)v : __int_as_float(v);
}

struct Box { float x1, y1, x2, y2; };

__device__ inline Box decode_clip(float4 r, float4 p, float W, float H) {
  float w = p.z - p.x, h = p.w - p.y;
  float cx = p.x + 0.5f * w, cy = p.y + 0.5f * h;
  float dx = r.x / 10.f, dy = r.y / 10.f;
  float dw = fminf(r.z / 5.f, XCLIP), dh = fminf(r.w / 5.f, XCLIP);
  float pcx = dx * w + cx, pcy = dy * h + cy;
  float pw = __expf(dw) * w, ph = __expf(dh) * h;
  Box b;
  b.x1 = fminf(fmaxf(pcx - 0.5f * pw, 0.f), W);
  b.y1 = fminf(fmaxf(pcy - 0.5f * ph, 0.f), H);
  b.x2 = fminf(fmaxf(pcx + 0.5f * pw, 0.f), W);
  b.y2 = fminf(fmaxf(pcy + 0.5f * ph, 0.f), H);
  return b;
}

__device__ inline float iou_f(const Box& a, const Box& b) {
  float area1 = (a.x2 - a.x1) * (a.y2 - a.y1);
  float area2 = (b.x2 - b.x1) * (b.y2 - b.y1);
  float lx = fmaxf(a.x1, b.x1), ly = fmaxf(a.y1, b.y1);
  float rx = fminf(a.x2, b.x2), ry = fminf(a.y2, b.y2);
  float w = fmaxf(rx - lx, 0.f), h = fmaxf(ry - ly, 0.f);
  float inter = w * h;
  return inter / (area1 + area2 - inter);
}

// K0: zero hist + counter.
__global__ __launch_bounds__(256) void k0_zero(unsigned int* __restrict__ hist) {
  int t = blockIdx.x * 256 + threadIdx.x;
  if (t < NBINS + 16) hist[t] = 0u;
}

// K1 v7: persistent blocks, double-buffered LDS tile, direct global->LDS DMA
// (global_load_lds x16B, no VGPR/scratch round trip). Next chunk's loads are
// issued BEFORE computing the current chunk; __syncthreads()'s vmcnt(0) drain
// lands after compute. Chunk stride = gridDim keeps the stream sequential.
__global__ __launch_bounds__(K1BLK) void k1_score(
    const float* __restrict__ logits, const float* __restrict__ reg,
    const float* __restrict__ prop, const int* __restrict__ ph,
    const int* __restrict__ pw, float* __restrict__ scores,
    int* __restrict__ labels, unsigned int* __restrict__ hist, int N) {
  __shared__ float tile[2][TILEF];        // 2 x 23552 B
  __shared__ unsigned int lh[NBINS];      // 4096 B
  const int t = threadIdx.x;
  const int wv = t >> 6, lane = t & 63;
  for (int i = t; i < NBINS; i += K1BLK) lh[i] = 0u;
  const float W = scalar_to_float(pw), H = scalar_to_float(ph);
  const int nchunks = (N + CHUNK - 1) / CHUNK;

  // Issue global->LDS DMA for chunk cc into buffer dst (wave-uniform LDS base,
  // per-lane global address; tail lanes clamp -> dup writes into the pad).
  auto stage = [&](int cc, float* dst) {
    const int nf  = min(CHUNK, N - cc * CHUNK) * 91;
    const int nf4 = nf >> 2;
    const float4* s4 = (const float4*)(logits + (size_t)cc * CHUNK * 91);
    #pragma unroll
    for (int k = 0; k < 6; ++k) {
      int base4 = (wv + (k << 2)) << 6;          // slot base (float4 units)
      if (base4 < nf4) {
        int g = base4 + lane;
        if (g > nf4 - 1) g = nf4 - 1;
        __builtin_amdgcn_global_load_lds(
            (const __attribute__((address_space(1))) void*)(s4 + g),
            (__attribute__((address_space(3))) void*)(dst + (base4 << 2)),
            16, 0, 0);
      }
    }
    for (int i = (nf4 << 2) + t; i < nf; i += K1BLK)   // generic scalar tail
      dst[i] = logits[(size_t)cc * CHUNK * 91 + i];
  };

  int c = blockIdx.x;
  int cur = 0;
  if (c < nchunks) stage(c, tile[0]);
  __syncthreads();                                  // drains vmcnt(0)
  while (c < nchunks) {
    const int cn = c + gridDim.x;
    if (cn < nchunks) stage(cn, tile[cur ^ 1]);     // in flight during compute
    const int rows = min(CHUNK, N - c * CHUNK);
    const int r = t >> 2, s = t & 3;
    if (r < rows) {
      const float* rowp = tile[cur] + r * 91;
      float mv = -3.402823466e38f; int mi = 1 << 20;
      float e0 = 0.f, e1 = 0.f;
      #pragma unroll
      for (int k = 0; k < 23; ++k) {
        int j = s + (k << 2);
        if (j < 91) {
          float v = rowp[j];
          float ex = __expf(v);
          if (k & 1) e1 += ex; else e0 += ex;
          if (v > mv) { mv = v; mi = j; }
        }
      }
      float e = e0 + e1;
      #pragma unroll
      for (int m = 1; m <= 2; m <<= 1) {
        float ov = __shfl_xor(mv, m, 64);
        int   oi = __shfl_xor(mi, m, 64);
        float oe = __shfl_xor(e, m, 64);
        e += oe;
        if (ov > mv || (ov == mv && oi < mi)) { mv = ov; mi = oi; }
      }
      if (s == 0) {
        float top1 = __expf(mv) / e;
        const int row = c * CHUNK + r;
        float4 rg = ((const float4*)reg)[row];
        float4 pp = ((const float4*)prop)[row];
        Box b = decode_clip(rg, pp, W, H);
        bool valid = (top1 > 0.05f) && ((b.x2 - b.x1) >= 0.01f) && ((b.y2 - b.y1) >= 0.01f);
        float sc = valid ? top1 : -1.f;
        scores[row] = sc;
        labels[row] = mi;
        if (sc > 0.f) {
          int bin = (int)(sc * (float)NBINS);
          if (bin > NBINS - 1) bin = NBINS - 1;
          atomicAdd(&lh[bin], 1u);
        }
      }
    }
    __syncthreads();   // vmcnt(0)+lgkmcnt(0) drain: prefetched tile ready
    cur ^= 1;
    c = cn;
  }
  __syncthreads();
  for (int i = t; i < NBINS; i += K1BLK) {
    unsigned int cu = lh[i];
    if (cu) atomicAdd(&hist[i], cu);
  }
}

// K2: wave-shuffle suffix scan (2 barriers), then compaction.
__global__ __launch_bounds__(1024) void k2_compact(
    const float* __restrict__ scores, const unsigned int* __restrict__ hist,
    unsigned long long* __restrict__ cand, unsigned int* __restrict__ counter, int N) {
  __shared__ unsigned int wsum[16];
  __shared__ unsigned int wtail[16];
  __shared__ int bstar;
  const int t = threadIdx.x;
  const int lane = t & 63, w = t >> 6;
  const unsigned int h0 = hist[t];
  unsigned int v = h0;
  #pragma unroll
  for (int m = 1; m < 64; m <<= 1) {
    unsigned int o = __shfl_down(v, m, 64);
    if (lane + m < 64) v += o;
  }
  if (lane == 0) wsum[w] = v;
  if (t == 0) bstar = 0;
  __syncthreads();
  if (w == 0) {
    unsigned int u = (lane < 16) ? wsum[lane] : 0u;
    unsigned int inc = u;
    #pragma unroll
    for (int m = 1; m < 16; m <<= 1) {
      unsigned int o = __shfl_down(inc, m, 64);
      if (lane + m < 16) inc += o;
    }
    if (lane < 16) wtail[lane] = inc - u;
  }
  __syncthreads();
  unsigned int St = v + wtail[w];
  unsigned int St1 = St - h0;
  if (St >= TARGETC && St1 < TARGETC) {
    int b = t;
    if (St > CAPC) b = t + 1;
    if (b > NBINS - 1) b = NBINS - 1;
    bstar = b;
  }
  __syncthreads();
  const int bs = bstar;
  for (int i = blockIdx.x * blockDim.x + t; i < N; i += gridDim.x * blockDim.x) {
    float sc = scores[i];
    if (sc > 0.f) {
      int bin = (int)(sc * (float)NBINS);
      if (bin > NBINS - 1) bin = NBINS - 1;
      if (bin >= bs) {
        unsigned int pos = atomicAdd(counter, 1u);
        if (pos < CAPC) {
          unsigned long long key =
              ((unsigned long long)__float_as_uint(sc) << 32) |
              (unsigned long long)(0xFFFFFFFFu - (unsigned int)i);
          cand[pos] = key;
        }
      }
    }
  }
}

// K3: single block. bitonic sort over next-pow2(count), chunked greedy NMS, output.
__global__ __launch_bounds__(1024) void k3_nms(
    const unsigned long long* __restrict__ cand, const unsigned int* __restrict__ counter,
    const float* __restrict__ reg, const float* __restrict__ prop,
    const int* __restrict__ labels, const int* __restrict__ ph,
    const int* __restrict__ pw, float* __restrict__ out) {
  __shared__ unsigned long long keys[CAPC];
  __shared__ Box kbox[DET];
  __shared__ int klab[DET];
  __shared__ float kscore[DET];
  __shared__ Box cbox[64];
  __shared__ int clab[64];
  __shared__ float cscore[64];
  __shared__ unsigned int supk[64];
  __shared__ unsigned int rowm[64][2];
  __shared__ int nkept;
  const int t = threadIdx.x;
  unsigned int cnt_u = *counter;
  int count = (cnt_u < (unsigned int)CAPC) ? (int)cnt_u : CAPC;
  int P = 1;
  while (P < count) P <<= 1;
  if (P < 2) P = 2;
  for (int i = t; i < P; i += 1024) keys[i] = (i < count) ? cand[i] : 0ULL;
  if (t == 0) nkept = 0;
  __syncthreads();
  for (int k = 2; k <= P; k <<= 1) {
    for (int j = k >> 1; j > 0; j >>= 1) {
      for (int i = t; i < P; i += 1024) {
        int ixj = i ^ j;
        if (ixj > i) {
          unsigned long long a = keys[i], b = keys[ixj];
          bool sw = ((i & k) == 0) ? (a < b) : (a > b);
          if (sw) { keys[i] = b; keys[ixj] = a; }
        }
      }
      __syncthreads();
    }
  }
  const float W = scalar_to_float(pw), H = scalar_to_float(ph);
  for (int base = 0; base < count && nkept < DET; base += 64) {
    int nc = count - base; if (nc > 64) nc = 64;
    if (t < 64) { supk[t] = 0u; rowm[t][0] = 0u; rowm[t][1] = 0u; }
    if (t < nc) {
      unsigned long long key = keys[base + t];
      int row = (int)(0xFFFFFFFFu - (unsigned int)(key & 0xFFFFFFFFULL));
      cscore[t] = __uint_as_float((unsigned int)(key >> 32));
      clab[t] = labels[row];
      float4 r = ((const float4*)reg)[row];
      float4 p = ((const float4*)prop)[row];
      cbox[t] = decode_clip(r, p, W, H);
    }
    __syncthreads();
    int nk = nkept;
    {
      int c = t >> 4, kk = t & 15;
      if (c < nc) {
        unsigned int hit = 0u;
        for (int j = kk; j < nk; j += 16) {
          if (clab[c] == klab[j] && iou_f(cbox[c], kbox[j]) > 0.5f) { hit = 1u; break; }
        }
        if (hit) atomicOr(&supk[c], 1u);
      }
    }
    for (int p4 = t; p4 < 64 * 64; p4 += 1024) {
      int a = p4 >> 6, b = p4 & 63;
      if (a < b && b < nc) {
        if (clab[a] == clab[b] && iou_f(cbox[a], cbox[b]) > 0.5f)
          atomicOr(&rowm[a][b >> 5], 1u << (b & 31));
      }
    }
    __syncthreads();
    if (t == 0) {
      unsigned int s0 = 0u, s1 = 0u;
      int nkl = nkept;
      for (int j = 0; j < nc && nkl < DET; ++j) {
        unsigned int bit = (j < 32) ? ((s0 >> j) & 1u) : ((s1 >> (j - 32)) & 1u);
        if (!supk[j] && !bit) {
          kbox[nkl] = cbox[j];
          klab[nkl] = clab[j];
          kscore[nkl] = cscore[j];
          ++nkl;
          s0 |= rowm[j][0];
          s1 |= rowm[j][1];
        }
      }
      nkept = nkl;
    }
    __syncthreads();
  }
  int nk = nkept;
  if (t < DET) {
    bool v = t < nk;
    Box b = v ? kbox[t] : Box{0.f, 0.f, 0.f, 0.f};
    out[t * 4 + 0] = b.x1;
    out[t * 4 + 1] = b.y1;
    out[t * 4 + 2] = b.x2;
    out[t * 4 + 3] = b.y2;
    out[400 + t] = v ? kscore[t] : 0.f;
    out[500 + t] = v ? (float)klab[t] : -1.f;
  }
}

extern "C" void kernel_launch(void* const* d_in, const int* in_sizes, int n_in,
                              void* d_out, int out_size, void* d_ws, size_t ws_size,
                              hipStream_t stream) {
  const float* logits = (const float*)d_in[0];
  const float* reg    = (const float*)d_in[1];
  const float* prop   = (const float*)d_in[2];
  const int*   ph     = (const int*)d_in[3];
  const int*   pw     = (const int*)d_in[4];
  float* out = (float*)d_out;

  const int N = in_sizes[1] / 4;

  char* ws = (char*)d_ws;
  float* scores = (float*)ws;                                  // N f32
  int* labels   = (int*)(ws + (size_t)N * 4);                  // N i32
  size_t off = (size_t)N * 8;
  off = (off + 255) & ~(size_t)255;
  unsigned int* hist = (unsigned int*)(ws + off);              // NBINS u32
  unsigned int* counter = hist + NBINS;                        // 1 u32
  unsigned long long* cand = (unsigned long long*)(ws + off + NBINS * 4 + 64); // CAPC u64

  k0_zero<<<(NBINS + 16 + 255) / 256, 256, 0, stream>>>(hist);
  k1_score<<<768, K1BLK, 0, stream>>>(logits, reg, prop, ph, pw, scores, labels, hist, N);
  k2_compact<<<256, 1024, 0, stream>>>(scores, hist, cand, counter, N);
  k3_nms<<<1, 1024, 0, stream>>>(cand, counter, reg, prop, labels, ph, pw, out);
}